// Round 1
// baseline (172.849 us; speedup 1.0000x reference)
//
#include <hip/hip_runtime.h>

#define T_DIM 256
#define B_DIM 256
#define I_DIM 256
#define H_DIM 256
#define COMB  512

// ws layout (float offsets)
#define OFF_W    0                               // [4][512] effective weights
#define OFF_SIG  2048                            // [4] sum of h-part weights
#define OFF_BETA 2052                            // [4] effective bias
#define OFF_A    2176                            // [T*B][4] x-part dots
#define OFF_HOUT (2176 + T_DIM * B_DIM * 4)      // [T*B] h scalar per (t,b)
#define OFF_CF   (OFF_HOUT + T_DIM * B_DIM)      // [B] final c
#define OFF_HF   (OFF_CF + B_DIM)                // [B] final h

// ---------------------------------------------------------------------------
// Kernel 1: fold the two linear layers per gate.
//   w_eff[g][j] = sum_k Wq_g[0][k] * W_g[k][j]   (j in [0,512))
//   sigma[g]    = sum_{j>=256} w_eff[g][j]        (h-part collapses: h const across H)
//   beta[g]     = sum_k Wq_g[0][k]*b_g[k] + bq_g[0]
// ---------------------------------------------------------------------------
__global__ __launch_bounds__(512) void k_weights(
    const float* W0, const float* b0, const float* Q0, const float* q0,
    const float* W1, const float* b1, const float* Q1, const float* q1,
    const float* W2, const float* b2, const float* Q2, const float* q2,
    const float* W3, const float* b3, const float* Q3, const float* q3,
    float* __restrict__ ws) {
  const float* W[4] = {W0, W1, W2, W3};
  const float* b[4] = {b0, b1, b2, b3};
  const float* Q[4] = {Q0, Q1, Q2, Q3};
  const float* q[4] = {q0, q1, q2, q3};
  const int g = blockIdx.x;
  const int j = threadIdx.x;  // 0..511
  const float* Wg = W[g];
  const float* Qg = Q[g];  // row 0 = first 256 floats

  float acc = 0.f;
  for (int k = 0; k < H_DIM; ++k)
    acc += Qg[k] * Wg[k * COMB + j];
  ws[OFF_W + g * COMB + j] = acc;

  __shared__ float red[512];
  // sigma: sum of w_eff over the h-part (j >= 256)
  red[j] = (j >= I_DIM) ? acc : 0.f;
  __syncthreads();
  for (int s = 256; s > 0; s >>= 1) {
    if (j < s) red[j] += red[j + s];
    __syncthreads();
  }
  if (j == 0) ws[OFF_SIG + g] = red[0];
  __syncthreads();
  // beta
  red[j] = (j < H_DIM) ? Qg[j] * b[g][j] : 0.f;
  __syncthreads();
  for (int s = 256; s > 0; s >>= 1) {
    if (j < s) red[j] += red[j + s];
    __syncthreads();
  }
  if (j == 0) ws[OFF_BETA + g] = red[0] + q[g][0];
}

// ---------------------------------------------------------------------------
// Kernel 2: A[t*B+b][g] = x[t,b,:] . w_eff[g][0:256]   (the memory-bound read)
// One wave per row, 4 rows per block.
// ---------------------------------------------------------------------------
__global__ __launch_bounds__(256) void k_dots(const float* __restrict__ x,
                                              const float* __restrict__ weff,
                                              float* __restrict__ A) {
  __shared__ float wx[4 * I_DIM];  // [g][256]
  const int tid = threadIdx.x;
#pragma unroll
  for (int e = 0; e < 4; ++e) {
    const int i = tid + e * 256;       // 0..1023, g-major
    const int g = i >> 8, j = i & 255;
    wx[i] = weff[g * COMB + j];
  }
  __syncthreads();

  const int wave = tid >> 6, lane = tid & 63;
  const int row = blockIdx.x * 4 + wave;
  const float4 xv =
      reinterpret_cast<const float4*>(x + (size_t)row * I_DIM)[lane];
  const float4* wx4 = reinterpret_cast<const float4*>(wx);
  const float4 w0 = wx4[0 * 64 + lane];
  const float4 w1 = wx4[1 * 64 + lane];
  const float4 w2 = wx4[2 * 64 + lane];
  const float4 w3 = wx4[3 * 64 + lane];
  float p0 = xv.x * w0.x + xv.y * w0.y + xv.z * w0.z + xv.w * w0.w;
  float p1 = xv.x * w1.x + xv.y * w1.y + xv.z * w1.z + xv.w * w1.w;
  float p2 = xv.x * w2.x + xv.y * w2.y + xv.z * w2.z + xv.w * w2.w;
  float p3 = xv.x * w3.x + xv.y * w3.y + xv.z * w3.z + xv.w * w3.w;
#pragma unroll
  for (int off = 32; off > 0; off >>= 1) {
    p0 += __shfl_down(p0, off, 64);
    p1 += __shfl_down(p1, off, 64);
    p2 += __shfl_down(p2, off, 64);
    p3 += __shfl_down(p3, off, 64);
  }
  if (lane == 0) {
    float4 r = {p0, p1, p2, p3};
    reinterpret_cast<float4*>(A)[row] = r;
  }
}

// ---------------------------------------------------------------------------
// Kernel 3: the sequential LSTM scan. One thread per batch sample.
// gate_n = act( cos^2( A[t,b,n] + Hs*sigma[n] + beta[n] ) )
// ---------------------------------------------------------------------------
__device__ __forceinline__ float fsigmoid(float x) {
  return 1.0f / (1.0f + __expf(-x));
}
__device__ __forceinline__ float ftanh(float x) {
  return 1.0f - 2.0f / (__expf(2.0f * x) + 1.0f);
}

__global__ __launch_bounds__(64) void k_scan(const float* __restrict__ A,
                                             const float* __restrict__ sig,
                                             const float* __restrict__ bet,
                                             float* __restrict__ Hout,
                                             float* __restrict__ Cf,
                                             float* __restrict__ Hf) {
  const int b = blockIdx.x * 64 + threadIdx.x;  // 0..255
  const float s0 = sig[0], s1 = sig[1], s2 = sig[2], s3 = sig[3];
  const float b0 = bet[0], b1 = bet[1], b2 = bet[2], b3 = bet[3];
  float C = 0.f, Hs = 0.f;
  const float4* A4 = reinterpret_cast<const float4*>(A);
  for (int t = 0; t < T_DIM; ++t) {
    const float4 a = A4[t * B_DIM + b];
    float ef = __cosf(a.x + Hs * s0 + b0);
    float ei = __cosf(a.y + Hs * s1 + b1);
    float eu = __cosf(a.z + Hs * s2 + b2);
    float eo = __cosf(a.w + Hs * s3 + b3);
    ef *= ef; ei *= ei; eu *= eu; eo *= eo;
    const float f = fsigmoid(ef);
    const float i = fsigmoid(ei);
    const float g = ftanh(eu);
    const float o = fsigmoid(eo);
    C = f * C + i * g;
    Hs = o * ftanh(C);
    Hout[t * B_DIM + b] = Hs;
  }
  Cf[b] = C;
  Hf[b] = Hs;
}

// ---------------------------------------------------------------------------
// Kernel 4: broadcast h scalar across H into outputs, hx, cx (memory-bound write)
// d_out = [outputs (T,B,H) | hx (B,H) | cx (B,H)], float32
// ---------------------------------------------------------------------------
__global__ __launch_bounds__(256) void k_bcast(const float* __restrict__ Hout,
                                               const float* __restrict__ Cf,
                                               const float* __restrict__ Hf,
                                               float* __restrict__ out) {
  const int i4 = blockIdx.x * 256 + threadIdx.x;
  const int N1 = T_DIM * B_DIM * H_DIM / 4;  // outputs in float4s
  const int N2 = N1 + B_DIM * H_DIM / 4;     // + hx
  const int N3 = N2 + B_DIM * H_DIM / 4;     // + cx
  if (i4 >= N3) return;
  float v;
  if (i4 < N1)
    v = Hout[i4 >> 6];            // (H/4)=64 float4s per (t,b)
  else if (i4 < N2)
    v = Hf[(i4 - N1) >> 6];
  else
    v = Cf[(i4 - N2) >> 6];
  const float4 r = {v, v, v, v};
  reinterpret_cast<float4*>(out)[i4] = r;
}

extern "C" void kernel_launch(void* const* d_in, const int* in_sizes, int n_in,
                              void* d_out, int out_size, void* d_ws,
                              size_t ws_size, hipStream_t stream) {
  const float* x = (const float*)d_in[0];
  const float* Wf = (const float*)d_in[1];
  const float* bf = (const float*)d_in[2];
  const float* Wfq = (const float*)d_in[3];
  const float* bfq = (const float*)d_in[4];
  const float* Wi = (const float*)d_in[5];
  const float* bi = (const float*)d_in[6];
  const float* Wiq = (const float*)d_in[7];
  const float* biq = (const float*)d_in[8];
  const float* Wu = (const float*)d_in[9];
  const float* bu = (const float*)d_in[10];
  const float* Wuq = (const float*)d_in[11];
  const float* buq = (const float*)d_in[12];
  const float* Wo = (const float*)d_in[13];
  const float* bo = (const float*)d_in[14];
  const float* Woq = (const float*)d_in[15];
  const float* boq = (const float*)d_in[16];

  float* ws = (float*)d_ws;
  float* out = (float*)d_out;

  k_weights<<<4, 512, 0, stream>>>(Wf, bf, Wfq, bfq, Wi, bi, Wiq, biq, Wu, bu,
                                   Wuq, buq, Wo, bo, Woq, boq, ws);
  k_dots<<<T_DIM * B_DIM / 4, 256, 0, stream>>>(x, ws + OFF_W, ws + OFF_A);
  k_scan<<<B_DIM / 64, 64, 0, stream>>>(ws + OFF_A, ws + OFF_SIG,
                                        ws + OFF_BETA, ws + OFF_HOUT,
                                        ws + OFF_CF, ws + OFF_HF);
  const int N3 = (T_DIM * B_DIM * H_DIM + 2 * B_DIM * H_DIM) / 4;
  k_bcast<<<(N3 + 255) / 256, 256, 0, stream>>>(ws + OFF_HOUT, ws + OFF_CF,
                                                ws + OFF_HF, out);
}

// Round 2
// 102.995 us; speedup vs baseline: 1.6782x; 1.6782x over previous
//
#include <hip/hip_runtime.h>

#define T_DIM 256
#define B_DIM 256
#define I_DIM 256
#define H_DIM 256
#define COMB  512
#define KCH   8      // k-chunks for weight fold
#define DEPTH 16     // scan software-pipeline depth

// ws layout (float offsets)
#define OFF_W    0                               // [4][512] effective weights
#define OFF_SIG  2048                            // [4] sum of h-part weights
#define OFF_BETA 2052                            // [4] effective bias
#define OFF_A    2176                            // [T*B][4] x-part dots (also reused as k_w1 partials)
#define OFF_HOUT (2176 + T_DIM * B_DIM * 4)      // [T*B] h scalar per (t,b)
#define OFF_CF   (OFF_HOUT + T_DIM * B_DIM)      // [B] final c
#define OFF_HF   (OFF_CF + B_DIM)                // [B] final h

// ---------------------------------------------------------------------------
// Kernel 1a: partial weight fold, parallel over k-chunks.
//   part[(g*KCH+c)*COMB + j] = sum_{k in chunk c} Wq_g[0][k] * W_g[k][j]
// 32 blocks -> 32 CUs fetching in parallel instead of 4.
// ---------------------------------------------------------------------------
__global__ __launch_bounds__(512) void k_w1(
    const float* W0, const float* Q0, const float* W1, const float* Q1,
    const float* W2, const float* Q2, const float* W3, const float* Q3,
    float* __restrict__ part) {
  const float* W[4] = {W0, W1, W2, W3};
  const float* Q[4] = {Q0, Q1, Q2, Q3};
  const int g = blockIdx.x >> 3, c = blockIdx.x & (KCH - 1);
  const int j = threadIdx.x;
  const float* Wg = W[g];
  const float* Qg = Q[g];
  float acc = 0.f;
  const int k0 = c * (H_DIM / KCH);
#pragma unroll 8
  for (int k = k0; k < k0 + H_DIM / KCH; ++k)
    acc += Qg[k] * Wg[k * COMB + j];
  part[(g * KCH + c) * COMB + j] = acc;
}

// ---------------------------------------------------------------------------
// Kernel 1b: reduce partials -> w_eff, sigma, beta.
// ---------------------------------------------------------------------------
__global__ __launch_bounds__(512) void k_w2(
    const float* __restrict__ part,
    const float* b0, const float* q0, const float* Q0,
    const float* b1, const float* q1, const float* Q1,
    const float* b2, const float* q2, const float* Q2,
    const float* b3, const float* q3, const float* Q3,
    float* __restrict__ ws) {
  const float* b[4] = {b0, b1, b2, b3};
  const float* q[4] = {q0, q1, q2, q3};
  const float* Q[4] = {Q0, Q1, Q2, Q3};
  const int g = blockIdx.x;
  const int j = threadIdx.x;
  float acc = 0.f;
#pragma unroll
  for (int c = 0; c < KCH; ++c) acc += part[(g * KCH + c) * COMB + j];
  ws[OFF_W + g * COMB + j] = acc;

  __shared__ float red[512];
  red[j] = (j >= I_DIM) ? acc : 0.f;
  __syncthreads();
  for (int s = 256; s > 0; s >>= 1) {
    if (j < s) red[j] += red[j + s];
    __syncthreads();
  }
  if (j == 0) ws[OFF_SIG + g] = red[0];
  __syncthreads();
  red[j] = (j < H_DIM) ? Q[g][j] * b[g][j] : 0.f;
  __syncthreads();
  for (int s = 256; s > 0; s >>= 1) {
    if (j < s) red[j] += red[j + s];
    __syncthreads();
  }
  if (j == 0) ws[OFF_BETA + g] = red[0] + q[g][0];
}

// ---------------------------------------------------------------------------
// Kernel 2: A[t*B+b][g] = x[t,b,:] . w_eff[g][0:256]   (memory-bound read)
// ---------------------------------------------------------------------------
__global__ __launch_bounds__(256) void k_dots(const float* __restrict__ x,
                                              const float* __restrict__ weff,
                                              float* __restrict__ A) {
  __shared__ float wx[4 * I_DIM];
  const int tid = threadIdx.x;
#pragma unroll
  for (int e = 0; e < 4; ++e) {
    const int i = tid + e * 256;
    const int g = i >> 8, j = i & 255;
    wx[i] = weff[g * COMB + j];
  }
  __syncthreads();

  const int wave = tid >> 6, lane = tid & 63;
  const int row = blockIdx.x * 4 + wave;
  const float4 xv =
      reinterpret_cast<const float4*>(x + (size_t)row * I_DIM)[lane];
  const float4* wx4 = reinterpret_cast<const float4*>(wx);
  const float4 w0 = wx4[0 * 64 + lane];
  const float4 w1 = wx4[1 * 64 + lane];
  const float4 w2 = wx4[2 * 64 + lane];
  const float4 w3 = wx4[3 * 64 + lane];
  float p0 = xv.x * w0.x + xv.y * w0.y + xv.z * w0.z + xv.w * w0.w;
  float p1 = xv.x * w1.x + xv.y * w1.y + xv.z * w1.z + xv.w * w1.w;
  float p2 = xv.x * w2.x + xv.y * w2.y + xv.z * w2.z + xv.w * w2.w;
  float p3 = xv.x * w3.x + xv.y * w3.y + xv.z * w3.z + xv.w * w3.w;
#pragma unroll
  for (int off = 32; off > 0; off >>= 1) {
    p0 += __shfl_down(p0, off, 64);
    p1 += __shfl_down(p1, off, 64);
    p2 += __shfl_down(p2, off, 64);
    p3 += __shfl_down(p3, off, 64);
  }
  if (lane == 0) {
    float4 r = {p0, p1, p2, p3};
    reinterpret_cast<float4*>(A)[row] = r;
  }
}

// ---------------------------------------------------------------------------
// Kernel 3: sequential LSTM scan, 16-deep software-pipelined loads.
// One thread per batch sample; buf[] statically indexed (full unroll) so it
// stays in VGPRs and the compiler keeps 16 global loads in flight.
// ---------------------------------------------------------------------------
__device__ __forceinline__ float fsigmoid(float x) {
  return 1.0f / (1.0f + __expf(-x));
}
__device__ __forceinline__ float ftanh(float x) {
  return 1.0f - 2.0f / (__expf(2.0f * x) + 1.0f);
}

__global__ __launch_bounds__(64) void k_scan(const float* __restrict__ A,
                                             const float* __restrict__ sig,
                                             const float* __restrict__ bet,
                                             float* __restrict__ Hout,
                                             float* __restrict__ Cf,
                                             float* __restrict__ Hf) {
  const int b = blockIdx.x * 64 + threadIdx.x;  // 0..255
  const float s0 = sig[0], s1 = sig[1], s2 = sig[2], s3 = sig[3];
  const float b0 = bet[0], b1 = bet[1], b2 = bet[2], b3 = bet[3];
  float C = 0.f, Hs = 0.f;
  const float4* A4 = reinterpret_cast<const float4*>(A);

  float4 buf[DEPTH];
#pragma unroll
  for (int j = 0; j < DEPTH; ++j) buf[j] = A4[j * B_DIM + b];

#define STEP(a, tt)                                        \
  {                                                        \
    float ef = __cosf(fmaf(Hs, s0, (a).x + b0));           \
    float ei = __cosf(fmaf(Hs, s1, (a).y + b1));           \
    float eu = __cosf(fmaf(Hs, s2, (a).z + b2));           \
    float eo = __cosf(fmaf(Hs, s3, (a).w + b3));           \
    ef *= ef; ei *= ei; eu *= eu; eo *= eo;                \
    const float f = fsigmoid(ef);                          \
    const float i = fsigmoid(ei);                          \
    const float g = ftanh(eu);                             \
    const float o = fsigmoid(eo);                          \
    C = f * C + i * g;                                     \
    Hs = o * ftanh(C);                                     \
    Hout[(tt) * B_DIM + b] = Hs;                           \
  }

  for (int t0 = 0; t0 < T_DIM - DEPTH; t0 += DEPTH) {
#pragma unroll
    for (int j = 0; j < DEPTH; ++j) {
      const float4 a = buf[j];
      buf[j] = A4[(t0 + DEPTH + j) * B_DIM + b];  // prefetch, 16 in flight
      STEP(a, t0 + j);
    }
  }
#pragma unroll
  for (int j = 0; j < DEPTH; ++j) {
    const float4 a = buf[j];
    STEP(a, T_DIM - DEPTH + j);
  }
#undef STEP

  Cf[b] = C;
  Hf[b] = Hs;
}

// ---------------------------------------------------------------------------
// Kernel 4: broadcast h scalar across H into outputs, hx, cx.
// ---------------------------------------------------------------------------
__global__ __launch_bounds__(256) void k_bcast(const float* __restrict__ Hout,
                                               const float* __restrict__ Cf,
                                               const float* __restrict__ Hf,
                                               float* __restrict__ out) {
  const int i4 = blockIdx.x * 256 + threadIdx.x;
  const int N1 = T_DIM * B_DIM * H_DIM / 4;
  const int N2 = N1 + B_DIM * H_DIM / 4;
  const int N3 = N2 + B_DIM * H_DIM / 4;
  if (i4 >= N3) return;
  float v;
  if (i4 < N1)
    v = Hout[i4 >> 6];
  else if (i4 < N2)
    v = Hf[(i4 - N1) >> 6];
  else
    v = Cf[(i4 - N2) >> 6];
  const float4 r = {v, v, v, v};
  reinterpret_cast<float4*>(out)[i4] = r;
}

extern "C" void kernel_launch(void* const* d_in, const int* in_sizes, int n_in,
                              void* d_out, int out_size, void* d_ws,
                              size_t ws_size, hipStream_t stream) {
  const float* x = (const float*)d_in[0];
  const float* Wf = (const float*)d_in[1];
  const float* bf = (const float*)d_in[2];
  const float* Wfq = (const float*)d_in[3];
  const float* bfq = (const float*)d_in[4];
  const float* Wi = (const float*)d_in[5];
  const float* bi = (const float*)d_in[6];
  const float* Wiq = (const float*)d_in[7];
  const float* biq = (const float*)d_in[8];
  const float* Wu = (const float*)d_in[9];
  const float* bu = (const float*)d_in[10];
  const float* Wuq = (const float*)d_in[11];
  const float* buq = (const float*)d_in[12];
  const float* Wo = (const float*)d_in[13];
  const float* bo = (const float*)d_in[14];
  const float* Woq = (const float*)d_in[15];
  const float* boq = (const float*)d_in[16];

  float* ws = (float*)d_ws;
  float* out = (float*)d_out;

  // Weight fold: partials land in the (not-yet-used) A region of ws.
  k_w1<<<4 * KCH, 512, 0, stream>>>(Wf, Wfq, Wi, Wiq, Wu, Wuq, Wo, Woq,
                                    ws + OFF_A);
  k_w2<<<4, 512, 0, stream>>>(ws + OFF_A, bf, bfq, Wfq, bi, biq, Wiq, bu, buq,
                              Wuq, bo, boq, Woq, ws);
  k_dots<<<T_DIM * B_DIM / 4, 256, 0, stream>>>(x, ws + OFF_W, ws + OFF_A);
  k_scan<<<B_DIM / 64, 64, 0, stream>>>(ws + OFF_A, ws + OFF_SIG,
                                        ws + OFF_BETA, ws + OFF_HOUT,
                                        ws + OFF_CF, ws + OFF_HF);
  const int N3 = (T_DIM * B_DIM * H_DIM + 2 * B_DIM * H_DIM) / 4;
  k_bcast<<<(N3 + 255) / 256, 256, 0, stream>>>(ws + OFF_HOUT, ws + OFF_CF,
                                                ws + OFF_HF, out);
}

// Round 3
// 86.567 us; speedup vs baseline: 1.9967x; 1.1898x over previous
//
#include <hip/hip_runtime.h>

#define T_DIM 256
#define B_DIM 256
#define I_DIM 256
#define H_DIM 256
#define COMB  512
#define KCH   8      // k-chunks for weight fold
#define DEPTH 16     // scan software-pipeline depth

// ws layout (float offsets)
#define OFF_W    0                               // [4][512] effective weights
#define OFF_SIG  2048                            // [4] sum of h-part weights
#define OFF_BETA 2052                            // [4] effective bias
#define OFF_A    2176                            // [T*B][4] gate pre-activations (2*(dot+beta))
#define OFF_HOUT (2176 + T_DIM * B_DIM * 4)      // [T*B] h scalar per (t,b)
#define OFF_CF   (OFF_HOUT + T_DIM * B_DIM)      // [B] final c
#define OFF_HF   (OFF_CF + B_DIM)                // [B] final h

// ---------------------------------------------------------------------------
// Kernel 1a: partial weight fold, parallel over k-chunks.
// ---------------------------------------------------------------------------
__global__ __launch_bounds__(512) void k_w1(
    const float* W0, const float* Q0, const float* W1, const float* Q1,
    const float* W2, const float* Q2, const float* W3, const float* Q3,
    float* __restrict__ part) {
  const float* W[4] = {W0, W1, W2, W3};
  const float* Q[4] = {Q0, Q1, Q2, Q3};
  const int g = blockIdx.x >> 3, c = blockIdx.x & (KCH - 1);
  const int j = threadIdx.x;
  const float* Wg = W[g];
  const float* Qg = Q[g];
  float acc = 0.f;
  const int k0 = c * (H_DIM / KCH);
#pragma unroll 8
  for (int k = k0; k < k0 + H_DIM / KCH; ++k)
    acc += Qg[k] * Wg[k * COMB + j];
  part[(g * KCH + c) * COMB + j] = acc;
}

// ---------------------------------------------------------------------------
// Kernel 1b: reduce partials -> w_eff, sigma, beta.
// ---------------------------------------------------------------------------
__global__ __launch_bounds__(512) void k_w2(
    const float* __restrict__ part,
    const float* b0, const float* q0, const float* Q0,
    const float* b1, const float* q1, const float* Q1,
    const float* b2, const float* q2, const float* Q2,
    const float* b3, const float* q3, const float* Q3,
    float* __restrict__ ws) {
  const float* b[4] = {b0, b1, b2, b3};
  const float* q[4] = {q0, q1, q2, q3};
  const float* Q[4] = {Q0, Q1, Q2, Q3};
  const int g = blockIdx.x;
  const int j = threadIdx.x;
  float acc = 0.f;
#pragma unroll
  for (int c = 0; c < KCH; ++c) acc += part[(g * KCH + c) * COMB + j];
  ws[OFF_W + g * COMB + j] = acc;

  __shared__ float red[512];
  red[j] = (j >= I_DIM) ? acc : 0.f;
  __syncthreads();
  for (int s = 256; s > 0; s >>= 1) {
    if (j < s) red[j] += red[j + s];
    __syncthreads();
  }
  if (j == 0) ws[OFF_SIG + g] = red[0];
  __syncthreads();
  red[j] = (j < H_DIM) ? Q[g][j] * b[g][j] : 0.f;
  __syncthreads();
  for (int s = 256; s > 0; s >>= 1) {
    if (j < s) red[j] += red[j + s];
    __syncthreads();
  }
  if (j == 0) ws[OFF_BETA + g] = red[0] + q[g][0];
}

// ---------------------------------------------------------------------------
// Kernel 2: A[t*B+b][g] = 2*( x[t,b,:].w_eff[g][0:256] + beta[g] )
// (pre-scaled by 2 so the scan's cos(2*theta) needs only one fma)
// ---------------------------------------------------------------------------
__global__ __launch_bounds__(256) void k_dots(const float* __restrict__ x,
                                              const float* __restrict__ weff,
                                              const float* __restrict__ bet,
                                              float* __restrict__ A) {
  __shared__ float wx[4 * I_DIM];
  const int tid = threadIdx.x;
#pragma unroll
  for (int e = 0; e < 4; ++e) {
    const int i = tid + e * 256;
    const int g = i >> 8, j = i & 255;
    wx[i] = weff[g * COMB + j];
  }
  __syncthreads();

  const int wave = tid >> 6, lane = tid & 63;
  const int row = blockIdx.x * 4 + wave;
  const float4 xv =
      reinterpret_cast<const float4*>(x + (size_t)row * I_DIM)[lane];
  const float4* wx4 = reinterpret_cast<const float4*>(wx);
  const float4 w0 = wx4[0 * 64 + lane];
  const float4 w1 = wx4[1 * 64 + lane];
  const float4 w2 = wx4[2 * 64 + lane];
  const float4 w3 = wx4[3 * 64 + lane];
  float p0 = xv.x * w0.x + xv.y * w0.y + xv.z * w0.z + xv.w * w0.w;
  float p1 = xv.x * w1.x + xv.y * w1.y + xv.z * w1.z + xv.w * w1.w;
  float p2 = xv.x * w2.x + xv.y * w2.y + xv.z * w2.z + xv.w * w2.w;
  float p3 = xv.x * w3.x + xv.y * w3.y + xv.z * w3.z + xv.w * w3.w;
#pragma unroll
  for (int off = 32; off > 0; off >>= 1) {
    p0 += __shfl_down(p0, off, 64);
    p1 += __shfl_down(p1, off, 64);
    p2 += __shfl_down(p2, off, 64);
    p3 += __shfl_down(p3, off, 64);
  }
  if (lane == 0) {
    float4 r = {2.f * (p0 + bet[0]), 2.f * (p1 + bet[1]),
                2.f * (p2 + bet[2]), 2.f * (p3 + bet[3])};
    reinterpret_cast<float4*>(A)[row] = r;
  }
}

// ---------------------------------------------------------------------------
// Kernel 3: sequential LSTM scan, polynomial gates.
//   E = cos^2(theta) = (1+u)/2, u = cos(2*theta)
//   sigmoid(E) -> deg-4 poly in u (Taylor @ E=0.5, max err ~4e-5 on u in [-1,1])
//   tanh(E)    -> deg-5 poly in u (max err ~1.4e-3)
//   tanh(C), C in [0,2.07] -> Pade(5,4) + native rcp (err <= 5e-5)
// Loop-carried chain: 1 fma + 1 v_cos + 4-5 fma + 1 fma + Pade(2 fma + rcp + 2 mul)
// ---------------------------------------------------------------------------
#define C0S 0.6224593312f
#define C1S 0.1175018561f
#define C2S (-0.0071946125f)
#define C3S (-0.0020074354f)
#define C4S 0.0002728000f

#define G0T 0.4621171573f
#define G1T 0.3932238600f
#define G2T (-0.0908577800f)
#define G3T (-0.0117749000f)
#define G4T 0.0102923100f
#define G5T (-0.0008507100f)

__device__ __forceinline__ float poly_sig(float u) {
  return fmaf(u, fmaf(u, fmaf(u, fmaf(u, C4S, C3S), C2S), C1S), C0S);
}
__device__ __forceinline__ float poly_tanhE(float u) {
  return fmaf(u, fmaf(u, fmaf(u, fmaf(u, fmaf(u, G5T, G4T), G3T), G2T), G1T), G0T);
}
__device__ __forceinline__ float pade_tanh(float x) {
  const float y = x * x;
  const float num = fmaf(y, fmaf(y, 1.0f, 105.0f), 945.0f);
  const float den = fmaf(y, fmaf(y, 15.0f, 420.0f), 945.0f);
  return x * num * __builtin_amdgcn_rcpf(den);
}

__global__ __launch_bounds__(64) void k_scan(const float* __restrict__ A,
                                             const float* __restrict__ sig,
                                             float* __restrict__ Hout,
                                             float* __restrict__ Cf,
                                             float* __restrict__ Hf) {
  const int b = blockIdx.x * 64 + threadIdx.x;  // 0..255
  const float s0 = 2.f * sig[0], s1 = 2.f * sig[1];
  const float s2 = 2.f * sig[2], s3 = 2.f * sig[3];
  float C = 0.f, Hs = 0.f;
  const float4* A4 = reinterpret_cast<const float4*>(A);

  float4 buf[DEPTH];
#pragma unroll
  for (int j = 0; j < DEPTH; ++j) buf[j] = A4[j * B_DIM + b];

#define STEP(a, tt)                                        \
  {                                                        \
    const float uf = __cosf(fmaf(Hs, s0, (a).x));          \
    const float ui = __cosf(fmaf(Hs, s1, (a).y));          \
    const float uu = __cosf(fmaf(Hs, s2, (a).z));          \
    const float uo = __cosf(fmaf(Hs, s3, (a).w));          \
    const float f = poly_sig(uf);                          \
    const float i = poly_sig(ui);                          \
    const float g = poly_tanhE(uu);                        \
    const float o = poly_sig(uo);                          \
    C = fmaf(f, C, i * g);                                 \
    Hs = o * pade_tanh(C);                                 \
    Hout[(tt) * B_DIM + b] = Hs;                           \
  }

  for (int t0 = 0; t0 < T_DIM - DEPTH; t0 += DEPTH) {
#pragma unroll
    for (int j = 0; j < DEPTH; ++j) {
      const float4 a = buf[j];
      buf[j] = A4[(t0 + DEPTH + j) * B_DIM + b];  // prefetch, 16 in flight
      STEP(a, t0 + j);
    }
  }
#pragma unroll
  for (int j = 0; j < DEPTH; ++j) {
    const float4 a = buf[j];
    STEP(a, T_DIM - DEPTH + j);
  }
#undef STEP

  Cf[b] = C;
  Hf[b] = Hs;
}

// ---------------------------------------------------------------------------
// Kernel 4: broadcast h scalar across H into outputs, hx, cx.
// ---------------------------------------------------------------------------
__global__ __launch_bounds__(256) void k_bcast(const float* __restrict__ Hout,
                                               const float* __restrict__ Cf,
                                               const float* __restrict__ Hf,
                                               float* __restrict__ out) {
  const int i4 = blockIdx.x * 256 + threadIdx.x;
  const int N1 = T_DIM * B_DIM * H_DIM / 4;
  const int N2 = N1 + B_DIM * H_DIM / 4;
  const int N3 = N2 + B_DIM * H_DIM / 4;
  if (i4 >= N3) return;
  float v;
  if (i4 < N1)
    v = Hout[i4 >> 6];
  else if (i4 < N2)
    v = Hf[(i4 - N1) >> 6];
  else
    v = Cf[(i4 - N2) >> 6];
  const float4 r = {v, v, v, v};
  reinterpret_cast<float4*>(out)[i4] = r;
}

extern "C" void kernel_launch(void* const* d_in, const int* in_sizes, int n_in,
                              void* d_out, int out_size, void* d_ws,
                              size_t ws_size, hipStream_t stream) {
  const float* x = (const float*)d_in[0];
  const float* Wf = (const float*)d_in[1];
  const float* bf = (const float*)d_in[2];
  const float* Wfq = (const float*)d_in[3];
  const float* bfq = (const float*)d_in[4];
  const float* Wi = (const float*)d_in[5];
  const float* bi = (const float*)d_in[6];
  const float* Wiq = (const float*)d_in[7];
  const float* biq = (const float*)d_in[8];
  const float* Wu = (const float*)d_in[9];
  const float* bu = (const float*)d_in[10];
  const float* Wuq = (const float*)d_in[11];
  const float* buq = (const float*)d_in[12];
  const float* Wo = (const float*)d_in[13];
  const float* bo = (const float*)d_in[14];
  const float* Woq = (const float*)d_in[15];
  const float* boq = (const float*)d_in[16];

  float* ws = (float*)d_ws;
  float* out = (float*)d_out;

  k_w1<<<4 * KCH, 512, 0, stream>>>(Wf, Wfq, Wi, Wiq, Wu, Wuq, Wo, Woq,
                                    ws + OFF_A);
  k_w2<<<4, 512, 0, stream>>>(ws + OFF_A, bf, bfq, Wfq, bi, biq, Wiq, bu, buq,
                              Wuq, bo, boq, Woq, ws);
  k_dots<<<T_DIM * B_DIM / 4, 256, 0, stream>>>(x, ws + OFF_W, ws + OFF_BETA,
                                                ws + OFF_A);
  k_scan<<<B_DIM / 64, 64, 0, stream>>>(ws + OFF_A, ws + OFF_SIG,
                                        ws + OFF_HOUT, ws + OFF_CF,
                                        ws + OFF_HF);
  const int N3 = (T_DIM * B_DIM * H_DIM + 2 * B_DIM * H_DIM) / 4;
  k_bcast<<<(N3 + 255) / 256, 256, 0, stream>>>(ws + OFF_HOUT, ws + OFF_CF,
                                                ws + OFF_HF, out);
}

// Round 4
// 58.796 us; speedup vs baseline: 2.9398x; 1.4723x over previous
//
#include <hip/hip_runtime.h>

#define T_DIM 256
#define B_DIM 256
#define I_DIM 256
#define H_DIM 256
#define COMB  512
#define KCH   8      // k-chunks for weight fold
#define DEPTH 16     // scan software-pipeline depth
#define CHUNK 32     // scan: output steps per parallel-in-time chunk
#define WARM  48     // scan: warm-up steps (error ~0.75^48 << threshold)
#define NCH   (T_DIM / CHUNK)

// ws layout (float offsets)
#define OFF_W    0                               // [4][512] effective weights
#define OFF_SIG  2048                            // [4] sum of h-part weights
#define OFF_BETA 2052                            // [4] effective bias
#define OFF_A    2176                            // [T*B][4] gate pre-activations 2*(dot+beta)
#define OFF_HOUT (2176 + T_DIM * B_DIM * 4)      // [T*B] h scalar per (t,b)
#define OFF_CF   (OFF_HOUT + T_DIM * B_DIM)      // [B] final c
#define OFF_HF   (OFF_CF + B_DIM)                // [B] final h

// ---------------------------------------------------------------------------
// Kernel 1a: partial weight fold, parallel over k-chunks.
// ---------------------------------------------------------------------------
__global__ __launch_bounds__(512) void k_w1(
    const float* W0, const float* Q0, const float* W1, const float* Q1,
    const float* W2, const float* Q2, const float* W3, const float* Q3,
    float* __restrict__ part) {
  const float* W[4] = {W0, W1, W2, W3};
  const float* Q[4] = {Q0, Q1, Q2, Q3};
  const int g = blockIdx.x >> 3, c = blockIdx.x & (KCH - 1);
  const int j = threadIdx.x;
  const float* Wg = W[g];
  const float* Qg = Q[g];
  float acc = 0.f;
  const int k0 = c * (H_DIM / KCH);
#pragma unroll 8
  for (int k = k0; k < k0 + H_DIM / KCH; ++k)
    acc += Qg[k] * Wg[k * COMB + j];
  part[(g * KCH + c) * COMB + j] = acc;
}

// ---------------------------------------------------------------------------
// Kernel 1b: reduce partials -> w_eff, sigma, beta.
// ---------------------------------------------------------------------------
__global__ __launch_bounds__(512) void k_w2(
    const float* __restrict__ part,
    const float* b0, const float* q0, const float* Q0,
    const float* b1, const float* q1, const float* Q1,
    const float* b2, const float* q2, const float* Q2,
    const float* b3, const float* q3, const float* Q3,
    float* __restrict__ ws) {
  const float* b[4] = {b0, b1, b2, b3};
  const float* q[4] = {q0, q1, q2, q3};
  const float* Q[4] = {Q0, Q1, Q2, Q3};
  const int g = blockIdx.x;
  const int j = threadIdx.x;
  float acc = 0.f;
#pragma unroll
  for (int c = 0; c < KCH; ++c) acc += part[(g * KCH + c) * COMB + j];
  ws[OFF_W + g * COMB + j] = acc;

  __shared__ float red[512];
  red[j] = (j >= I_DIM) ? acc : 0.f;
  __syncthreads();
  for (int s = 256; s > 0; s >>= 1) {
    if (j < s) red[j] += red[j + s];
    __syncthreads();
  }
  if (j == 0) ws[OFF_SIG + g] = red[0];
  __syncthreads();
  red[j] = (j < H_DIM) ? Q[g][j] * b[g][j] : 0.f;
  __syncthreads();
  for (int s = 256; s > 0; s >>= 1) {
    if (j < s) red[j] += red[j + s];
    __syncthreads();
  }
  if (j == 0) ws[OFF_BETA + g] = red[0] + q[g][0];
}

// ---------------------------------------------------------------------------
// Kernel 2: A[t*B+b][g] = 2*( x[t,b,:].w_eff[g][0:256] + beta[g] )
// ---------------------------------------------------------------------------
__global__ __launch_bounds__(256) void k_dots(const float* __restrict__ x,
                                              const float* __restrict__ weff,
                                              const float* __restrict__ bet,
                                              float* __restrict__ A) {
  __shared__ float wx[4 * I_DIM];
  const int tid = threadIdx.x;
#pragma unroll
  for (int e = 0; e < 4; ++e) {
    const int i = tid + e * 256;
    const int g = i >> 8, j = i & 255;
    wx[i] = weff[g * COMB + j];
  }
  __syncthreads();

  const int wave = tid >> 6, lane = tid & 63;
  const int row = blockIdx.x * 4 + wave;
  const float4 xv =
      reinterpret_cast<const float4*>(x + (size_t)row * I_DIM)[lane];
  const float4* wx4 = reinterpret_cast<const float4*>(wx);
  const float4 w0 = wx4[0 * 64 + lane];
  const float4 w1 = wx4[1 * 64 + lane];
  const float4 w2 = wx4[2 * 64 + lane];
  const float4 w3 = wx4[3 * 64 + lane];
  float p0 = xv.x * w0.x + xv.y * w0.y + xv.z * w0.z + xv.w * w0.w;
  float p1 = xv.x * w1.x + xv.y * w1.y + xv.z * w1.z + xv.w * w1.w;
  float p2 = xv.x * w2.x + xv.y * w2.y + xv.z * w2.z + xv.w * w2.w;
  float p3 = xv.x * w3.x + xv.y * w3.y + xv.z * w3.z + xv.w * w3.w;
#pragma unroll
  for (int off = 32; off > 0; off >>= 1) {
    p0 += __shfl_down(p0, off, 64);
    p1 += __shfl_down(p1, off, 64);
    p2 += __shfl_down(p2, off, 64);
    p3 += __shfl_down(p3, off, 64);
  }
  if (lane == 0) {
    float4 r = {2.f * (p0 + bet[0]), 2.f * (p1 + bet[1]),
                2.f * (p2 + bet[2]), 2.f * (p3 + bet[3])};
    reinterpret_cast<float4*>(A)[row] = r;
  }
}

// ---------------------------------------------------------------------------
// Kernel 3: parallel-in-time LSTM scan.
// Block c handles output steps [c*CHUNK, (c+1)*CHUNK) for all 256 samples,
// warm-started WARM steps earlier from (C,Hs)=(0,0); contraction (f<=0.731)
// makes the warm-up error ~0.75^48 ~ 2e-6. 16-deep load pipeline; all NS
// values (32/64/80) are multiples of DEPTH.
// ---------------------------------------------------------------------------
#define C0S 0.6224593312f
#define C1S 0.1175018561f
#define C2S (-0.0071946125f)
#define C3S (-0.0020074354f)
#define C4S 0.0002728000f

#define G0T 0.4621171573f
#define G1T 0.3932238600f
#define G2T (-0.0908577800f)
#define G3T (-0.0117749000f)
#define G4T 0.0102923100f
#define G5T (-0.0008507100f)

__device__ __forceinline__ float poly_sig(float u) {
  return fmaf(u, fmaf(u, fmaf(u, fmaf(u, C4S, C3S), C2S), C1S), C0S);
}
__device__ __forceinline__ float poly_tanhE(float u) {
  return fmaf(u, fmaf(u, fmaf(u, fmaf(u, fmaf(u, G5T, G4T), G3T), G2T), G1T), G0T);
}
__device__ __forceinline__ float pade_tanh(float x) {
  const float y = x * x;
  const float num = fmaf(y, fmaf(y, 1.0f, 105.0f), 945.0f);
  const float den = fmaf(y, fmaf(y, 15.0f, 420.0f), 945.0f);
  return x * num * __builtin_amdgcn_rcpf(den);
}

__global__ __launch_bounds__(256) void k_scan(const float* __restrict__ A,
                                              const float* __restrict__ sig,
                                              float* __restrict__ Hout,
                                              float* __restrict__ Cf,
                                              float* __restrict__ Hf) {
  const int b = threadIdx.x;       // 0..255
  const int c = blockIdx.x;        // chunk 0..NCH-1
  const int t0 = c * CHUNK;
  const int w0 = (t0 - WARM > 0) ? (t0 - WARM) : 0;
  const int NS = t0 + CHUNK - w0;  // 32, 64, or 80 — all multiples of 16

  const float s0 = 2.f * sig[0], s1 = 2.f * sig[1];
  const float s2 = 2.f * sig[2], s3 = 2.f * sig[3];
  float C = 0.f, Hs = 0.f;
  const float4* A4 = reinterpret_cast<const float4*>(A);

  float4 buf[DEPTH];
#pragma unroll
  for (int j = 0; j < DEPTH; ++j) buf[j] = A4[(w0 + j) * B_DIM + b];

#define STEP(a, tt)                                        \
  {                                                        \
    const float uf = __cosf(fmaf(Hs, s0, (a).x));          \
    const float ui = __cosf(fmaf(Hs, s1, (a).y));          \
    const float uu = __cosf(fmaf(Hs, s2, (a).z));          \
    const float uo = __cosf(fmaf(Hs, s3, (a).w));          \
    const float f = poly_sig(uf);                          \
    const float i = poly_sig(ui);                          \
    const float g = poly_tanhE(uu);                        \
    const float o = poly_sig(uo);                          \
    C = fmaf(f, C, i * g);                                 \
    Hs = o * pade_tanh(C);                                 \
    if ((tt) >= t0) Hout[(tt) * B_DIM + b] = Hs;           \
  }

  for (int sb = 0; sb < NS; sb += DEPTH) {
#pragma unroll
    for (int j = 0; j < DEPTH; ++j) {
      const float4 a = buf[j];
      if (sb + DEPTH + j < NS)
        buf[j] = A4[(w0 + sb + DEPTH + j) * B_DIM + b];  // prefetch
      STEP(a, w0 + sb + j);
    }
  }
#undef STEP

  if (c == NCH - 1) {
    Cf[b] = C;
    Hf[b] = Hs;
  }
}

// ---------------------------------------------------------------------------
// Kernel 4: broadcast h scalar across H into outputs, hx, cx.
// ---------------------------------------------------------------------------
__global__ __launch_bounds__(256) void k_bcast(const float* __restrict__ Hout,
                                               const float* __restrict__ Cf,
                                               const float* __restrict__ Hf,
                                               float* __restrict__ out) {
  const int i4 = blockIdx.x * 256 + threadIdx.x;
  const int N1 = T_DIM * B_DIM * H_DIM / 4;
  const int N2 = N1 + B_DIM * H_DIM / 4;
  const int N3 = N2 + B_DIM * H_DIM / 4;
  if (i4 >= N3) return;
  float v;
  if (i4 < N1)
    v = Hout[i4 >> 6];
  else if (i4 < N2)
    v = Hf[(i4 - N1) >> 6];
  else
    v = Cf[(i4 - N2) >> 6];
  const float4 r = {v, v, v, v};
  reinterpret_cast<float4*>(out)[i4] = r;
}

extern "C" void kernel_launch(void* const* d_in, const int* in_sizes, int n_in,
                              void* d_out, int out_size, void* d_ws,
                              size_t ws_size, hipStream_t stream) {
  const float* x = (const float*)d_in[0];
  const float* Wf = (const float*)d_in[1];
  const float* bf = (const float*)d_in[2];
  const float* Wfq = (const float*)d_in[3];
  const float* bfq = (const float*)d_in[4];
  const float* Wi = (const float*)d_in[5];
  const float* bi = (const float*)d_in[6];
  const float* Wiq = (const float*)d_in[7];
  const float* biq = (const float*)d_in[8];
  const float* Wu = (const float*)d_in[9];
  const float* bu = (const float*)d_in[10];
  const float* Wuq = (const float*)d_in[11];
  const float* buq = (const float*)d_in[12];
  const float* Wo = (const float*)d_in[13];
  const float* bo = (const float*)d_in[14];
  const float* Woq = (const float*)d_in[15];
  const float* boq = (const float*)d_in[16];

  float* ws = (float*)d_ws;
  float* out = (float*)d_out;

  k_w1<<<4 * KCH, 512, 0, stream>>>(Wf, Wfq, Wi, Wiq, Wu, Wuq, Wo, Woq,
                                    ws + OFF_A);
  k_w2<<<4, 512, 0, stream>>>(ws + OFF_A, bf, bfq, Wfq, bi, biq, Wiq, bu, buq,
                              Wuq, bo, boq, Woq, ws);
  k_dots<<<T_DIM * B_DIM / 4, 256, 0, stream>>>(x, ws + OFF_W, ws + OFF_BETA,
                                                ws + OFF_A);
  k_scan<<<NCH, 256, 0, stream>>>(ws + OFF_A, ws + OFF_SIG, ws + OFF_HOUT,
                                  ws + OFF_CF, ws + OFF_HF);
  const int N3 = (T_DIM * B_DIM * H_DIM + 2 * B_DIM * H_DIM) / 4;
  k_bcast<<<(N3 + 255) / 256, 256, 0, stream>>>(ws + OFF_HOUT, ws + OFF_CF,
                                                ws + OFF_HF, out);
}

// Round 5
// 53.002 us; speedup vs baseline: 3.2612x; 1.1093x over previous
//
#include <hip/hip_runtime.h>

#define T_DIM 256
#define B_DIM 256
#define I_DIM 256
#define H_DIM 256
#define COMB  512
#define DEPTH 8      // scan software-pipeline depth
#define CHUNK 8      // scan: output steps per parallel-in-time chunk
#define WARM  32     // scan: warm-up steps (error ~0.75^32 ~ 1e-4 << threshold)
#define NCH   (T_DIM / CHUNK)

// ws layout (float offsets)
#define OFF_W    0                               // [4][256] effective x-part weights
#define OFF_SIG  1024                            // [4] 2*sigma (h-part row sums)
#define OFF_BETA 1028                            // [4] beta
#define OFF_A    1152                            // [T*B][4] gate pre-activations 2*(dot+beta)
#define OFF_HOUT (OFF_A + T_DIM * B_DIM * 4)     // [T*B] h scalar per (t,b)
#define OFF_CF   (OFF_HOUT + T_DIM * B_DIM)      // [B] final c
#define OFF_HF   (OFF_CF + B_DIM)                // [B] final h

// ---------------------------------------------------------------------------
// Kernel 1: weight fold, one kernel. Block = (gate g, j-half). 256 threads:
//   thread (jq = tid&63, ks = tid>>6) accumulates float4 over k = 4m+ks.
//   half 0 stores w_eff[g][0:256] (x-part) and beta; half 1 reduces to 2*sigma.
// ---------------------------------------------------------------------------
__global__ __launch_bounds__(256) void k_wfold(
    const float* W0, const float* b0, const float* Q0, const float* q0,
    const float* W1, const float* b1, const float* Q1, const float* q1,
    const float* W2, const float* b2, const float* Q2, const float* q2,
    const float* W3, const float* b3, const float* Q3, const float* q3,
    float* __restrict__ ws) {
  const float* W[4] = {W0, W1, W2, W3};
  const float* Bv[4] = {b0, b1, b2, b3};
  const float* Q[4] = {Q0, Q1, Q2, Q3};
  const float* qv[4] = {q0, q1, q2, q3};
  const int g = blockIdx.x >> 1, half = blockIdx.x & 1;
  const int tid = threadIdx.x;
  const int jq = tid & 63;   // float4 column within the 256-wide half
  const int ks = tid >> 6;   // k-subset 0..3 (wave-uniform)
  const float* Wg = W[g];
  const float* Qg = Q[g];

  float4 acc = {0.f, 0.f, 0.f, 0.f};
#pragma unroll 8
  for (int m = 0; m < 64; ++m) {
    const int k = 4 * m + ks;
    const float qk = Qg[k];
    const float4 w = *reinterpret_cast<const float4*>(
        Wg + (size_t)k * COMB + half * 256 + 4 * jq);
    acc.x = fmaf(qk, w.x, acc.x);
    acc.y = fmaf(qk, w.y, acc.y);
    acc.z = fmaf(qk, w.z, acc.z);
    acc.w = fmaf(qk, w.w, acc.w);
  }

  __shared__ float4 red4[256];
  __shared__ float reds[256];
  red4[tid] = acc;
  __syncthreads();

  float4 s = {0.f, 0.f, 0.f, 0.f};
  if (tid < 64) {
    const float4 a0 = red4[tid], a1 = red4[tid + 64];
    const float4 a2 = red4[tid + 128], a3 = red4[tid + 192];
    s.x = a0.x + a1.x + a2.x + a3.x;
    s.y = a0.y + a1.y + a2.y + a3.y;
    s.z = a0.z + a1.z + a2.z + a3.z;
    s.w = a0.w + a1.w + a2.w + a3.w;
    if (half == 0)
      reinterpret_cast<float4*>(ws + OFF_W + g * 256)[tid] = s;
  }

  // sigma (half 1): total sum of s over j
  reds[tid] = (tid < 64) ? (s.x + s.y + s.z + s.w) : 0.f;
  __syncthreads();
  for (int st = 128; st > 0; st >>= 1) {
    if (tid < st) reds[tid] += reds[tid + st];
    __syncthreads();
  }
  if (tid == 0 && half == 1) ws[OFF_SIG + g] = 2.f * reds[0];
  __syncthreads();

  // beta (half 0): sum_k Qg[k]*b[g][k] + q[g][0]
  reds[tid] = Qg[tid] * Bv[g][tid];
  __syncthreads();
  for (int st = 128; st > 0; st >>= 1) {
    if (tid < st) reds[tid] += reds[tid + st];
    __syncthreads();
  }
  if (tid == 0 && half == 0) ws[OFF_BETA + g] = reds[0] + qv[g][0];
}

// ---------------------------------------------------------------------------
// Kernel 2: A[t*B+b][g] = 2*( x[t,b,:].w_eff[g][0:256] + beta[g] )
// ---------------------------------------------------------------------------
__global__ __launch_bounds__(256) void k_dots(const float* __restrict__ x,
                                              const float* __restrict__ weff,
                                              const float* __restrict__ bet,
                                              float* __restrict__ A) {
  __shared__ float wx[4 * I_DIM];
  const int tid = threadIdx.x;
#pragma unroll
  for (int e = 0; e < 4; ++e) wx[tid + e * 256] = weff[tid + e * 256];
  __syncthreads();

  const int wave = tid >> 6, lane = tid & 63;
  const int row = blockIdx.x * 4 + wave;
  const float4 xv =
      reinterpret_cast<const float4*>(x + (size_t)row * I_DIM)[lane];
  const float4* wx4 = reinterpret_cast<const float4*>(wx);
  const float4 w0 = wx4[0 * 64 + lane];
  const float4 w1 = wx4[1 * 64 + lane];
  const float4 w2 = wx4[2 * 64 + lane];
  const float4 w3 = wx4[3 * 64 + lane];
  float p0 = xv.x * w0.x + xv.y * w0.y + xv.z * w0.z + xv.w * w0.w;
  float p1 = xv.x * w1.x + xv.y * w1.y + xv.z * w1.z + xv.w * w1.w;
  float p2 = xv.x * w2.x + xv.y * w2.y + xv.z * w2.z + xv.w * w2.w;
  float p3 = xv.x * w3.x + xv.y * w3.y + xv.z * w3.z + xv.w * w3.w;
#pragma unroll
  for (int off = 32; off > 0; off >>= 1) {
    p0 += __shfl_down(p0, off, 64);
    p1 += __shfl_down(p1, off, 64);
    p2 += __shfl_down(p2, off, 64);
    p3 += __shfl_down(p3, off, 64);
  }
  if (lane == 0) {
    float4 r = {2.f * (p0 + bet[0]), 2.f * (p1 + bet[1]),
                2.f * (p2 + bet[2]), 2.f * (p3 + bet[3])};
    reinterpret_cast<float4*>(A)[row] = r;
  }
}

// ---------------------------------------------------------------------------
// Kernel 3: parallel-in-time LSTM scan. 32 chunks of 8 output steps, each
// warm-started up to 32 steps earlier from (0,0). NS in {8,16,24,32,40}, all
// multiples of DEPTH=8.
// ---------------------------------------------------------------------------
#define C0S 0.6224593312f
#define C1S 0.1175018561f
#define C2S (-0.0071946125f)
#define C3S (-0.0020074354f)
#define C4S 0.0002728000f

#define G0T 0.4621171573f
#define G1T 0.3932238600f
#define G2T (-0.0908577800f)
#define G3T (-0.0117749000f)
#define G4T 0.0102923100f
#define G5T (-0.0008507100f)

__device__ __forceinline__ float poly_sig(float u) {
  return fmaf(u, fmaf(u, fmaf(u, fmaf(u, C4S, C3S), C2S), C1S), C0S);
}
__device__ __forceinline__ float poly_tanhE(float u) {
  return fmaf(u, fmaf(u, fmaf(u, fmaf(u, fmaf(u, G5T, G4T), G3T), G2T), G1T), G0T);
}
__device__ __forceinline__ float pade_tanh(float x) {
  const float y = x * x;
  const float num = fmaf(y, fmaf(y, 1.0f, 105.0f), 945.0f);
  const float den = fmaf(y, fmaf(y, 15.0f, 420.0f), 945.0f);
  return x * num * __builtin_amdgcn_rcpf(den);
}

__global__ __launch_bounds__(256) void k_scan(const float* __restrict__ A,
                                              const float* __restrict__ sig,
                                              float* __restrict__ Hout,
                                              float* __restrict__ Cf,
                                              float* __restrict__ Hf) {
  const int b = threadIdx.x;       // 0..255
  const int c = blockIdx.x;        // chunk 0..NCH-1
  const int t0 = c * CHUNK;
  const int w0 = (t0 - WARM > 0) ? (t0 - WARM) : 0;
  const int NS = t0 + CHUNK - w0;  // multiple of 8

  const float s0 = sig[0], s1 = sig[1], s2 = sig[2], s3 = sig[3];
  float C = 0.f, Hs = 0.f;
  const float4* A4 = reinterpret_cast<const float4*>(A);

  float4 buf[DEPTH];
#pragma unroll
  for (int j = 0; j < DEPTH; ++j) buf[j] = A4[(w0 + j) * B_DIM + b];

#define STEP(a, tt)                                        \
  {                                                        \
    const float uf = __cosf(fmaf(Hs, s0, (a).x));          \
    const float ui = __cosf(fmaf(Hs, s1, (a).y));          \
    const float uu = __cosf(fmaf(Hs, s2, (a).z));          \
    const float uo = __cosf(fmaf(Hs, s3, (a).w));          \
    const float f = poly_sig(uf);                          \
    const float i = poly_sig(ui);                          \
    const float g = poly_tanhE(uu);                        \
    const float o = poly_sig(uo);                          \
    C = fmaf(f, C, i * g);                                 \
    Hs = o * pade_tanh(C);                                 \
    if ((tt) >= t0) Hout[(tt) * B_DIM + b] = Hs;           \
  }

  for (int sb = 0; sb < NS; sb += DEPTH) {
#pragma unroll
    for (int j = 0; j < DEPTH; ++j) {
      const float4 a = buf[j];
      if (sb + DEPTH + j < NS)
        buf[j] = A4[(w0 + sb + DEPTH + j) * B_DIM + b];  // prefetch
      STEP(a, w0 + sb + j);
    }
  }
#undef STEP

  if (c == NCH - 1) {
    Cf[b] = C;
    Hf[b] = Hs;
  }
}

// ---------------------------------------------------------------------------
// Kernel 4: broadcast h scalar across H into outputs, hx, cx.
// ---------------------------------------------------------------------------
__global__ __launch_bounds__(256) void k_bcast(const float* __restrict__ Hout,
                                               const float* __restrict__ Cf,
                                               const float* __restrict__ Hf,
                                               float* __restrict__ out) {
  const int i4 = blockIdx.x * 256 + threadIdx.x;
  const int N1 = T_DIM * B_DIM * H_DIM / 4;
  const int N2 = N1 + B_DIM * H_DIM / 4;
  const int N3 = N2 + B_DIM * H_DIM / 4;
  if (i4 >= N3) return;
  float v;
  if (i4 < N1)
    v = Hout[i4 >> 6];
  else if (i4 < N2)
    v = Hf[(i4 - N1) >> 6];
  else
    v = Cf[(i4 - N2) >> 6];
  const float4 r = {v, v, v, v};
  reinterpret_cast<float4*>(out)[i4] = r;
}

extern "C" void kernel_launch(void* const* d_in, const int* in_sizes, int n_in,
                              void* d_out, int out_size, void* d_ws,
                              size_t ws_size, hipStream_t stream) {
  const float* x = (const float*)d_in[0];
  const float* Wf = (const float*)d_in[1];
  const float* bf = (const float*)d_in[2];
  const float* Wfq = (const float*)d_in[3];
  const float* bfq = (const float*)d_in[4];
  const float* Wi = (const float*)d_in[5];
  const float* bi = (const float*)d_in[6];
  const float* Wiq = (const float*)d_in[7];
  const float* biq = (const float*)d_in[8];
  const float* Wu = (const float*)d_in[9];
  const float* bu = (const float*)d_in[10];
  const float* Wuq = (const float*)d_in[11];
  const float* buq = (const float*)d_in[12];
  const float* Wo = (const float*)d_in[13];
  const float* bo = (const float*)d_in[14];
  const float* Woq = (const float*)d_in[15];
  const float* boq = (const float*)d_in[16];

  float* ws = (float*)d_ws;
  float* out = (float*)d_out;

  k_wfold<<<8, 256, 0, stream>>>(Wf, bf, Wfq, bfq, Wi, bi, Wiq, biq, Wu, bu,
                                 Wuq, buq, Wo, bo, Woq, boq, ws);
  k_dots<<<T_DIM * B_DIM / 4, 256, 0, stream>>>(x, ws + OFF_W, ws + OFF_BETA,
                                                ws + OFF_A);
  k_scan<<<NCH, 256, 0, stream>>>(ws + OFF_A, ws + OFF_SIG, ws + OFF_HOUT,
                                  ws + OFF_CF, ws + OFF_HF);
  const int N3 = (T_DIM * B_DIM * H_DIM + 2 * B_DIM * H_DIM) / 4;
  k_bcast<<<(N3 + 255) / 256, 256, 0, stream>>>(ws + OFF_HOUT, ws + OFF_CF,
                                                ws + OFF_HF, out);
}